// Round 3
// baseline (582.565 us; speedup 1.0000x reference)
//
#include <hip/hip_runtime.h>
#include <math.h>

// Problem constants (reference setup_inputs): N=8192, K=32, D=128, fp32.
constexpr int NN = 8192;
constexpr int K  = 32;
constexpr int D  = 128;
constexpr int DP = D + 4;      // padded LDS row stride (floats): rotates banks by 4/row
constexpr float ALPHA = 0.2f;
constexpr float MASKV = -9e15f;
constexpr float EPS   = 1e-8f;

__device__ __forceinline__ float dot4(const float4 a, const float4 b) {
    return fmaf(a.x, b.x, fmaf(a.y, b.y, fmaf(a.z, b.z, a.w * b.w)));
}

// ---------------------------------------------------------------------------
// Fully fused 2-layer GAT-relation. One block per n (row-independent problem).
// Layer 1:  hd[k,:] = dst[n,k,:]@W_bot + b  (4.3 G-MAC core, fp32 VALU,
//           e-split across thread halves so W_bot is read ONCE per block)
//           e1 via cosine(h1,rel) decomposition; softmax; x1 = agg + src;
//           cache A=dot(hd,rel), B=||hd||^2, R=max(||rel||,eps) in LDS.
// Layer 2:  dot(sW2,hd) = dot(dst, W_bot.sW2) + dot(sW2,b) -> no hd rebuild;
//           e2 from cached A,B,R; softmax; out = agg2 + x1.
// dst/rel read from HBM exactly once (~262 MB total kernel traffic).
// ---------------------------------------------------------------------------
__global__ __launch_bounds__(256) void gat_fused(
    const float* __restrict__ src,
    const float* __restrict__ dst,
    const float* __restrict__ rel,
    const float* __restrict__ W,
    const float* __restrict__ b,
    const int*   __restrict__ adj,
    float* __restrict__ out)
{
    __shared__ __align__(16) float dst_s[K * DP];
    __shared__ __align__(16) float rel_s[K * DP];
    __shared__ __align__(16) float hd_s [K * DP];
    __shared__ __align__(16) float x_s [D];   // holds src, then x1
    __shared__ __align__(16) float sW_s[D];   // sW1, then sW2
    __shared__ __align__(16) float g_s [D];   // g2 = W_bot . sW2
    __shared__ float e_s[K], att_s[K], A_s[K], B_s[K], R_s[K];
    __shared__ int   adj_s[K];

    const int n = blockIdx.x;
    const int t = threadIdx.x;
    const int d  = t & (D - 1);   // 0..127
    const int eh = t >> 7;        // e-half: 0 or 1

    const float* dstn = dst + (size_t)n * K * D;
    const float* reln = rel + (size_t)n * K * D;

    // ---- stage src, adj, dst, rel (coalesced float4) ----
    if (t < D / 4) ((float4*)x_s)[t] = ((const float4*)(src + (size_t)n * D))[t];
    if (t >= 64 && t < 64 + K) adj_s[t - 64] = adj[n * K + (t - 64)];
    #pragma unroll
    for (int j = 0; j < 4; ++j) {
        const int idx = t + 256 * j;           // [0, K*D/4)
        const int row = idx >> 5, col = idx & 31;
        *(float4*)(dst_s + row * DP + 4 * col) = ((const float4*)dstn)[idx];
        *(float4*)(rel_s + row * DP + 4 * col) = ((const float4*)reln)[idx];
    }
    __syncthreads();

    // ---- sW1 = src @ W_top (t<128; W coalesced over d; read once/block) ----
    if (t < D) {
        float s = 0.f;
        #pragma unroll 1
        for (int e4 = 0; e4 < D / 4; ++e4) {
            const float4 sv = ((const float4*)x_s)[e4];
            s = fmaf(sv.x, W[(4 * e4 + 0) * D + d], s);
            s = fmaf(sv.y, W[(4 * e4 + 1) * D + d], s);
            s = fmaf(sv.z, W[(4 * e4 + 2) * D + d], s);
            s = fmaf(sv.w, W[(4 * e4 + 3) * D + d], s);
        }
        sW_s[d] = s;
    }

    // ---- hd = dst @ W_bot + b : thread owns (d, e-half); all 32 k in regs.
    // W_bot element (e,d) is loaded by exactly ONE thread -> 64 KB L2/block.
    // dst_s reads are wave-uniform -> LDS broadcast (conflict-free).
    {
        float acc[K];
        #pragma unroll
        for (int k = 0; k < K; ++k) acc[k] = 0.f;
        const float* Wb = W + D * D + (size_t)(64 * eh) * D;  // this half's rows
        #pragma unroll 2
        for (int e4 = 0; e4 < 16; ++e4) {       // 16 quads of e per half
            const float w0 = Wb[(4 * e4 + 0) * D + d];
            const float w1 = Wb[(4 * e4 + 1) * D + d];
            const float w2 = Wb[(4 * e4 + 2) * D + d];
            const float w3 = Wb[(4 * e4 + 3) * D + d];
            const int f = 16 * eh + e4;         // float4 index into row
            #pragma unroll
            for (int k = 0; k < K; ++k) {
                const float4 dv = *(const float4*)(dst_s + k * DP + 4 * f);
                acc[k] = fmaf(dv.x, w0, acc[k]);
                acc[k] = fmaf(dv.y, w1, acc[k]);
                acc[k] = fmaf(dv.z, w2, acc[k]);
                acc[k] = fmaf(dv.w, w3, acc[k]);
            }
        }
        // combine halves: eh=1 writes partials, eh=0 adds its own + bias
        if (eh == 1) {
            #pragma unroll
            for (int k = 0; k < K; ++k) hd_s[k * DP + d] = acc[k];
        }
        __syncthreads();
        if (eh == 0) {
            const float bd = b[d];
            #pragma unroll
            for (int k = 0; k < K; ++k)
                hd_s[k * DP + d] = hd_s[k * DP + d] + acc[k] + bd;
        }
    }
    __syncthreads();

    // lane mapping for per-k dots: k = 8*wave + (l&7), elem-quad q = (l&63)>>3.
    // b128 bank-group = ((kc&7)+q) mod 8 -> 8 lanes/group, balanced (bus floor).
    const int kc = 8 * (t >> 6) + (t & 7);
    const int q  = (t & 63) >> 3;

    // ---- layer-1 per-(n,k) scalars + e1 ----
    {
        float a_ = 0.f, bb = 0.f, r2 = 0.f, sr = 0.f, sh = 0.f, ss = 0.f;
        #pragma unroll
        for (int j = 0; j < 4; ++j) {
            const int f = q + 8 * j;
            const float4 rv = *(const float4*)(rel_s + kc * DP + 4 * f);
            const float4 hv = *(const float4*)(hd_s + kc * DP + 4 * f);
            const float4 sv = ((const float4*)sW_s)[f];
            a_ += dot4(hv, rv);  bb += dot4(hv, hv);  r2 += dot4(rv, rv);
            sr += dot4(sv, rv);  sh += dot4(sv, hv);  ss += dot4(sv, sv);
        }
        #pragma unroll
        for (int m = 8; m < 64; m <<= 1) {
            a_ += __shfl_xor(a_, m);  bb += __shfl_xor(bb, m);
            r2 += __shfl_xor(r2, m);  sr += __shfl_xor(sr, m);
            sh += __shfl_xor(sh, m);  ss += __shfl_xor(ss, m);
        }
        if (q == 0) {
            const float R   = fmaxf(sqrtf(r2), EPS);
            const float hh  = ss + 2.f * sh + bb;          // ||h1||^2
            const float den = fmaxf(sqrtf(hh), EPS) * R;
            float e = (sr + a_) / den;
            e = e > 0.f ? e : ALPHA * e;                   // LeakyReLU
            if (adj_s[kc] <= 0) e = MASKV;                 // mask
            e_s[kc] = e;  A_s[kc] = a_;  B_s[kc] = bb;  R_s[kc] = R;
        }
    }
    __syncthreads();

    // ---- softmax1 (32 lanes of wave 0) ----
    if (t < K) {
        float v = e_s[t], m = v;
        #pragma unroll
        for (int s = 16; s > 0; s >>= 1) m = fmaxf(m, __shfl_xor(m, s));
        const float p = expf(v - m);
        float sm = p;
        #pragma unroll
        for (int s = 16; s > 0; s >>= 1) sm += __shfl_xor(sm, s);
        att_s[t] = p / sm;
    }
    __syncthreads();

    // ---- x1 = agg1 + src ----
    if (t < D) {
        float agg = 0.f;
        #pragma unroll
        for (int k = 0; k < K; ++k) agg = fmaf(att_s[k], dst_s[k * DP + d], agg);
        x_s[d] = agg + x_s[d];
    }
    __syncthreads();

    // ---- sW2 = x1 @ W_top ----
    if (t < D) {
        float s = 0.f;
        #pragma unroll 1
        for (int e4 = 0; e4 < D / 4; ++e4) {
            const float4 sv = ((const float4*)x_s)[e4];
            s = fmaf(sv.x, W[(4 * e4 + 0) * D + d], s);
            s = fmaf(sv.y, W[(4 * e4 + 1) * D + d], s);
            s = fmaf(sv.z, W[(4 * e4 + 2) * D + d], s);
            s = fmaf(sv.w, W[(4 * e4 + 3) * D + d], s);
        }
        sW_s[d] = s;
    }
    __syncthreads();

    // ---- g2[e] = dot(W_bot[e,:], sW2) : lane streams its own row (L2-hot) ----
    if (t < D) {
        const float* Wr = W + (size_t)(D + d) * D;
        float g = 0.f;
        #pragma unroll 1
        for (int j = 0; j < D / 4; ++j)
            g += dot4(((const float4*)Wr)[j], ((const float4*)sW_s)[j]);
        g_s[d] = g;
    }
    __syncthreads();

    // ---- layer-2 scalars + e2 (reuse cached A,B,R) ----
    {
        float sr = 0.f, sdg = 0.f, ss = 0.f, sb = 0.f;
        #pragma unroll
        for (int j = 0; j < 4; ++j) {
            const int f = q + 8 * j;
            const float4 rv = *(const float4*)(rel_s + kc * DP + 4 * f);
            const float4 dv = *(const float4*)(dst_s + kc * DP + 4 * f);
            const float4 sv = ((const float4*)sW_s)[f];
            const float4 gv = ((const float4*)g_s)[f];
            const float4 bv = ((const float4*)b)[f];
            sr += dot4(sv, rv);  sdg += dot4(dv, gv);
            ss += dot4(sv, sv);  sb  += dot4(sv, bv);
        }
        #pragma unroll
        for (int m = 8; m < 64; m <<= 1) {
            sr += __shfl_xor(sr, m);  sdg += __shfl_xor(sdg, m);
            ss += __shfl_xor(ss, m);  sb  += __shfl_xor(sb, m);
        }
        if (q == 0) {
            const float sh  = sdg + sb;                    // dot(sW2, hd)
            const float hh  = ss + 2.f * sh + B_s[kc];     // ||h2||^2
            const float den = fmaxf(sqrtf(hh), EPS) * R_s[kc];
            float e = (sr + A_s[kc]) / den;
            e = e > 0.f ? e : ALPHA * e;
            if (adj_s[kc] <= 0) e = MASKV;
            e_s[kc] = e;
        }
    }
    __syncthreads();

    // ---- softmax2 ----
    if (t < K) {
        float v = e_s[t], m = v;
        #pragma unroll
        for (int s = 16; s > 0; s >>= 1) m = fmaxf(m, __shfl_xor(m, s));
        const float p = expf(v - m);
        float sm = p;
        #pragma unroll
        for (int s = 16; s > 0; s >>= 1) sm += __shfl_xor(sm, s);
        att_s[t] = p / sm;
    }
    __syncthreads();

    // ---- out = agg2 + x1 ----
    if (t < D) {
        float agg = 0.f;
        #pragma unroll
        for (int k = 0; k < K; ++k) agg = fmaf(att_s[k], dst_s[k * DP + d], agg);
        out[(size_t)n * D + d] = agg + x_s[d];
    }
}

extern "C" void kernel_launch(void* const* d_in, const int* in_sizes, int n_in,
                              void* d_out, int out_size, void* d_ws, size_t ws_size,
                              hipStream_t stream) {
    const float* src = (const float*)d_in[0];
    const float* dst = (const float*)d_in[1];
    const float* rel = (const float*)d_in[2];
    const float* W   = (const float*)d_in[3];
    const float* b   = (const float*)d_in[4];
    const int*   adj = (const int*)d_in[5];
    float* out = (float*)d_out;

    gat_fused<<<NN, 256, 0, stream>>>(src, dst, rel, W, b, adj, out);
}

// Round 4
// 379.487 us; speedup vs baseline: 1.5351x; 1.5351x over previous
//
#include <hip/hip_runtime.h>
#include <math.h>

// Problem constants (reference setup_inputs): N=8192, K=32, D=128, fp32.
constexpr int NN = 8192;
constexpr int K  = 32;
constexpr int D  = 128;
constexpr int DP = D + 4;      // padded LDS row stride (floats)
constexpr float ALPHA = 0.2f;
constexpr float MASKV = -9e15f;
constexpr float EPS   = 1e-8f;

typedef __bf16 bf16x8 __attribute__((ext_vector_type(8)));
typedef float  f32x4  __attribute__((ext_vector_type(4)));

__device__ __forceinline__ float dot4(const float4 a, const float4 b) {
    return fmaf(a.x, b.x, fmaf(a.y, b.y, fmaf(a.z, b.z, a.w * b.w)));
}

// ---------------------------------------------------------------------------
// Pre-kernel: convert W_bot (rows D..2D-1 of W) into MFMA-fragment-ordered
// bf16 hi/lo planes in d_ws. Fragment (s,n): lane l, elem j holds
// W[D + 32s + 8*(l>>4) + j][16n + (l&15)]  ->  flat idx ((s*8+n)*64+l)*8+j.
// ---------------------------------------------------------------------------
__global__ __launch_bounds__(256) void conv_w(const float* __restrict__ W,
                                              __bf16* __restrict__ whi,
                                              __bf16* __restrict__ wlo) {
    const int idx = blockIdx.x * 256 + threadIdx.x;      // 16384 total
    const int j = idx & 7, l = (idx >> 3) & 63, nt = (idx >> 9) & 7, s = idx >> 12;
    const int e = 32 * s + 8 * (l >> 4) + j;
    const int c = 16 * nt + (l & 15);
    const float x = W[(size_t)(D + e) * D + c];
    const __bf16 h = (__bf16)x;
    whi[idx] = h;
    wlo[idx] = (__bf16)(x - (float)h);
}

// ---------------------------------------------------------------------------
// Fused 2-layer GAT-relation, one block per n.
// hd = dst@W_bot + b via split-bf16 MFMA (3 products, err ~2^-17).
// Layer 2 uses hd_s directly: dot(sW2, h2-part) = dot(sW2, hd) — no g2 GEMV.
// ---------------------------------------------------------------------------
__global__ __launch_bounds__(256) void gat_fused(
    const float* __restrict__ src,
    const float* __restrict__ dst,
    const float* __restrict__ rel,
    const float* __restrict__ W,
    const float* __restrict__ b,
    const int*   __restrict__ adj,
    const __bf16* __restrict__ whi,
    const __bf16* __restrict__ wlo,
    float* __restrict__ out)
{
    __shared__ __align__(16) float dst_s[K * DP];
    __shared__ __align__(16) float rel_s[K * DP];
    __shared__ __align__(16) float hd_s [K * DP];
    __shared__ __align__(16) float x_s [D];    // src, then x1
    __shared__ __align__(16) float sW_s[D];    // sW1, then sW2
    __shared__ __align__(16) float sWp[2 * D]; // GEMV e-split partials
    __shared__ __align__(16) float b_s[D];
    __shared__ float e_s[K], att_s[K], A_s[K], B_s[K], R_s[K];
    __shared__ int   adj_s[K];

    const int n  = blockIdx.x;
    const int t  = threadIdx.x;
    const int w  = t >> 6;        // wave 0..3
    const int l  = t & 63;        // lane
    const int lr = l & 15;        // tile row/col index
    const int lk = l >> 4;        // k-block 0..3

    const float* dstn = dst + (size_t)n * K * D;
    const float* reln = rel + (size_t)n * K * D;

    // ---- phase 1: stage src, b, adj, dst, rel ----
    if (t < 32)       ((float4*)x_s)[t]      = ((const float4*)(src + (size_t)n * D))[t];
    else if (t < 64)  ((float4*)b_s)[t - 32] = ((const float4*)b)[t - 32];
    else if (t < 96)  adj_s[t - 64] = adj[n * K + (t - 64)];
    #pragma unroll
    for (int jj = 0; jj < 4; ++jj) {
        const int idx = t + 256 * jj;          // [0, K*D/4)
        const int row = idx >> 5, col = idx & 31;
        *(float4*)(dst_s + row * DP + 4 * col) = ((const float4*)dstn)[idx];
        *(float4*)(rel_s + row * DP + 4 * col) = ((const float4*)reln)[idx];
    }
    __syncthreads();

    // ---- phase 2a: hd[k,d] = dst@W_bot via split-bf16 MFMA ----
    // wave w owns dtiles {2w, 2w+1} x ktiles {0,1}. 48 MFMA/wave.
    {
        f32x4 acc00 = {0,0,0,0}, acc01 = {0,0,0,0};   // [ni=0][m=0/1]
        f32x4 acc10 = {0,0,0,0}, acc11 = {0,0,0,0};   // [ni=1][m=0/1]
        #pragma unroll
        for (int ks = 0; ks < 4; ++ks) {               // e-steps of 32
            const int cb = 32 * ks + 8 * lk;
            // A-fragments (m=0: rows 0-15, m=1: rows 16-31), in-register cvt
            bf16x8 ah0, al0, ah1, al1;
            {
                const float* p0 = dst_s + lr * DP + cb;
                const float* p1 = dst_s + (16 + lr) * DP + cb;
                const f32x4 x0 = *(const f32x4*)p0, x1 = *(const f32x4*)(p0 + 4);
                const f32x4 y0 = *(const f32x4*)p1, y1 = *(const f32x4*)(p1 + 4);
                #pragma unroll
                for (int jj = 0; jj < 4; ++jj) {
                    float v; __bf16 h;
                    v = x0[jj]; h = (__bf16)v; ah0[jj]     = h; al0[jj]     = (__bf16)(v - (float)h);
                    v = x1[jj]; h = (__bf16)v; ah0[4 + jj] = h; al0[4 + jj] = (__bf16)(v - (float)h);
                    v = y0[jj]; h = (__bf16)v; ah1[jj]     = h; al1[jj]     = (__bf16)(v - (float)h);
                    v = y1[jj]; h = (__bf16)v; ah1[4 + jj] = h; al1[4 + jj] = (__bf16)(v - (float)h);
                }
            }
            #pragma unroll
            for (int ni = 0; ni < 2; ++ni) {
                const int nt = 2 * w + ni;
                const size_t fo = (size_t)((ks * 8 + nt) * 64 + l) * 8;
                const bf16x8 bh = *(const bf16x8*)(whi + fo);
                const bf16x8 bl = *(const bf16x8*)(wlo + fo);
                f32x4& a0 = ni ? acc10 : acc00;
                f32x4& a1 = ni ? acc11 : acc01;
                a0 = __builtin_amdgcn_mfma_f32_16x16x32_bf16(ah0, bh, a0, 0, 0, 0);
                a0 = __builtin_amdgcn_mfma_f32_16x16x32_bf16(ah0, bl, a0, 0, 0, 0);
                a0 = __builtin_amdgcn_mfma_f32_16x16x32_bf16(al0, bh, a0, 0, 0, 0);
                a1 = __builtin_amdgcn_mfma_f32_16x16x32_bf16(ah1, bh, a1, 0, 0, 0);
                a1 = __builtin_amdgcn_mfma_f32_16x16x32_bf16(ah1, bl, a1, 0, 0, 0);
                a1 = __builtin_amdgcn_mfma_f32_16x16x32_bf16(al1, bh, a1, 0, 0, 0);
            }
        }
        // C/D layout (m89): col = lane&15, row = (lane>>4)*4 + reg. +bias here.
        #pragma unroll
        for (int ni = 0; ni < 2; ++ni) {
            const int nt = 2 * w + ni;
            const float bc = b_s[16 * nt + lr];
            const f32x4 a0 = ni ? acc10 : acc00;
            const f32x4 a1 = ni ? acc11 : acc01;
            #pragma unroll
            for (int r = 0; r < 4; ++r) {
                hd_s[(4 * lk + r) * DP + 16 * nt + lr]      = a0[r] + bc;
                hd_s[(16 + 4 * lk + r) * DP + 16 * nt + lr] = a1[r] + bc;
            }
        }
    }

    // ---- phase 2b: sW1 partials (e-split over thread halves) ----
    {
        const int dd = t & (D - 1), eh = t >> 7;
        float acc = 0.f;
        const float* Wt = W + (size_t)(64 * eh) * D + dd;
        #pragma unroll 8
        for (int e = 0; e < 64; ++e)
            acc = fmaf(x_s[64 * eh + e], Wt[(size_t)e * D], acc);
        sWp[eh * D + dd] = acc;
    }
    __syncthreads();
    if (t < D) sW_s[t] = sWp[t] + sWp[D + t];
    __syncthreads();

    // lane mapping for per-k dots: kc = 8*wave + (l&7), quad q = l>>3.
    const int kc = 8 * w + (l & 7);
    const int q  = l >> 3;

    // ---- layer-1 scalars + e1; cache A, B, R ----
    {
        float a_ = 0.f, bb = 0.f, r2 = 0.f, sr = 0.f, sh = 0.f, ss = 0.f;
        #pragma unroll
        for (int jj = 0; jj < 4; ++jj) {
            const int f = q + 8 * jj;
            const float4 rv = *(const float4*)(rel_s + kc * DP + 4 * f);
            const float4 hv = *(const float4*)(hd_s + kc * DP + 4 * f);
            const float4 sv = ((const float4*)sW_s)[f];
            a_ += dot4(hv, rv);  bb += dot4(hv, hv);  r2 += dot4(rv, rv);
            sr += dot4(sv, rv);  sh += dot4(sv, hv);  ss += dot4(sv, sv);
        }
        #pragma unroll
        for (int m = 8; m < 64; m <<= 1) {
            a_ += __shfl_xor(a_, m);  bb += __shfl_xor(bb, m);
            r2 += __shfl_xor(r2, m);  sr += __shfl_xor(sr, m);
            sh += __shfl_xor(sh, m);  ss += __shfl_xor(ss, m);
        }
        if (q == 0) {
            const float R   = fmaxf(sqrtf(r2), EPS);
            const float hh  = ss + 2.f * sh + bb;
            const float den = fmaxf(sqrtf(hh), EPS) * R;
            float e = (sr + a_) / den;
            e = e > 0.f ? e : ALPHA * e;
            if (adj_s[kc] <= 0) e = MASKV;
            e_s[kc] = e;  A_s[kc] = a_;  B_s[kc] = bb;  R_s[kc] = R;
        }
    }
    __syncthreads();

    // ---- softmax1 ----
    if (t < K) {
        float v = e_s[t], m = v;
        #pragma unroll
        for (int s = 16; s > 0; s >>= 1) m = fmaxf(m, __shfl_xor(m, s));
        const float p = expf(v - m);
        float sm = p;
        #pragma unroll
        for (int s = 16; s > 0; s >>= 1) sm += __shfl_xor(sm, s);
        att_s[t] = p / sm;
    }
    __syncthreads();

    // ---- x1 = agg1 + src ----
    if (t < D) {
        float agg = 0.f;
        #pragma unroll
        for (int k = 0; k < K; ++k) agg = fmaf(att_s[k], dst_s[k * DP + t], agg);
        x_s[t] = agg + x_s[t];
    }
    __syncthreads();

    // ---- sW2 partials ----
    {
        const int dd = t & (D - 1), eh = t >> 7;
        float acc = 0.f;
        const float* Wt = W + (size_t)(64 * eh) * D + dd;
        #pragma unroll 8
        for (int e = 0; e < 64; ++e)
            acc = fmaf(x_s[64 * eh + e], Wt[(size_t)e * D], acc);
        sWp[eh * D + dd] = acc;
    }
    __syncthreads();
    if (t < D) sW_s[t] = sWp[t] + sWp[D + t];
    __syncthreads();

    // ---- layer-2 scalars + e2 (dot(sW2,hd) direct from hd_s) ----
    {
        float sr = 0.f, sh = 0.f, ss = 0.f;
        #pragma unroll
        for (int jj = 0; jj < 4; ++jj) {
            const int f = q + 8 * jj;
            const float4 rv = *(const float4*)(rel_s + kc * DP + 4 * f);
            const float4 hv = *(const float4*)(hd_s + kc * DP + 4 * f);
            const float4 sv = ((const float4*)sW_s)[f];
            sr += dot4(sv, rv);  sh += dot4(sv, hv);  ss += dot4(sv, sv);
        }
        #pragma unroll
        for (int m = 8; m < 64; m <<= 1) {
            sr += __shfl_xor(sr, m);  sh += __shfl_xor(sh, m);  ss += __shfl_xor(ss, m);
        }
        if (q == 0) {
            const float hh  = ss + 2.f * sh + B_s[kc];
            const float den = fmaxf(sqrtf(hh), EPS) * R_s[kc];
            float e = (sr + A_s[kc]) / den;
            e = e > 0.f ? e : ALPHA * e;
            if (adj_s[kc] <= 0) e = MASKV;
            e_s[kc] = e;
        }
    }
    __syncthreads();

    // ---- softmax2 ----
    if (t < K) {
        float v = e_s[t], m = v;
        #pragma unroll
        for (int s = 16; s > 0; s >>= 1) m = fmaxf(m, __shfl_xor(m, s));
        const float p = expf(v - m);
        float sm = p;
        #pragma unroll
        for (int s = 16; s > 0; s >>= 1) sm += __shfl_xor(sm, s);
        att_s[t] = p / sm;
    }
    __syncthreads();

    // ---- out = agg2 + x1 ----
    if (t < D) {
        float agg = 0.f;
        #pragma unroll
        for (int k = 0; k < K; ++k) agg = fmaf(att_s[k], dst_s[k * DP + t], agg);
        out[(size_t)n * D + t] = agg + x_s[t];
    }
}

extern "C" void kernel_launch(void* const* d_in, const int* in_sizes, int n_in,
                              void* d_out, int out_size, void* d_ws, size_t ws_size,
                              hipStream_t stream) {
    const float* src = (const float*)d_in[0];
    const float* dst = (const float*)d_in[1];
    const float* rel = (const float*)d_in[2];
    const float* W   = (const float*)d_in[3];
    const float* b   = (const float*)d_in[4];
    const int*   adj = (const int*)d_in[5];
    float* out = (float*)d_out;

    __bf16* whi = (__bf16*)d_ws;            // 16384 bf16 = 32 KB
    __bf16* wlo = whi + 4 * 8 * 64 * 8;     // +32 KB

    conv_w<<<64, 256, 0, stream>>>(W, whi, wlo);
    gat_fused<<<NN, 256, 0, stream>>>(src, dst, rel, W, b, adj, whi, wlo, out);
}

// Round 5
// 373.793 us; speedup vs baseline: 1.5585x; 1.0152x over previous
//
#include <hip/hip_runtime.h>
#include <math.h>

// Problem constants (reference setup_inputs): N=8192, K=32, D=128, fp32.
constexpr int NN = 8192;
constexpr int K  = 32;
constexpr int D  = 128;
constexpr int DP = D + 4;      // padded LDS row stride (floats)
constexpr float ALPHA = 0.2f;
constexpr float MASKV = -9e15f;
constexpr float EPS   = 1e-8f;

typedef __bf16 bf16x8 __attribute__((ext_vector_type(8)));
typedef float  f32x4  __attribute__((ext_vector_type(4)));

__device__ __forceinline__ float dot4(const float4 a, const float4 b) {
    return fmaf(a.x, b.x, fmaf(a.y, b.y, fmaf(a.z, b.z, a.w * b.w)));
}

// ---------------------------------------------------------------------------
// Pre-kernel: W_bot (rows D..2D-1 of W) -> MFMA-fragment-ordered bf16 hi/lo.
// Fragment (s,nt): lane l, elem j holds W[D + 32s + 8*(l>>4) + j][16nt + (l&15)]
// flat idx ((s*8+nt)*64+l)*8+j.
// ---------------------------------------------------------------------------
__global__ __launch_bounds__(256) void conv_w(const float* __restrict__ W,
                                              __bf16* __restrict__ whi,
                                              __bf16* __restrict__ wlo) {
    const int idx = blockIdx.x * 256 + threadIdx.x;      // 16384 total
    const int j = idx & 7, l = (idx >> 3) & 63, nt = (idx >> 9) & 7, s = idx >> 12;
    const int e = 32 * s + 8 * (l >> 4) + j;
    const int c = 16 * nt + (l & 15);
    const float x = W[(size_t)(D + e) * D + c];
    const __bf16 h = (__bf16)x;
    whi[idx] = h;
    wlo[idx] = (__bf16)(x - (float)h);
}

// ---------------------------------------------------------------------------
// Fused 2-layer GAT-relation, one block of 512 threads (8 waves) per n.
// Wave w owns d-tile nt=w in the MFMA phase and k-rows {4w..4w+3} (full d)
// in the dot phases — no cross-wave partial combines.
// hd = dst@W_bot + b via split-bf16 MFMA (3 products, err ~2^-17).
// Layer 2 reuses hd_s: dot(sW2,hd) directly; A,B,R cached from layer 1.
// ---------------------------------------------------------------------------
__global__ __launch_bounds__(512) void gat_fused(
    const float* __restrict__ src,
    const float* __restrict__ dst,
    const float* __restrict__ rel,
    const float* __restrict__ W,
    const float* __restrict__ b,
    const int*   __restrict__ adj,
    const __bf16* __restrict__ whi,
    const __bf16* __restrict__ wlo,
    float* __restrict__ out)
{
    __shared__ __align__(16) float dst_s[K * DP];
    __shared__ __align__(16) float rel_s[K * DP];
    __shared__ __align__(16) float hd_s [K * DP];
    __shared__ __align__(16) float x_s [D];     // src, then x1
    __shared__ __align__(16) float sW_s[D];     // sW1, then sW2
    __shared__ __align__(16) float sWp[4 * D];  // GEMV e-split partials
    __shared__ __align__(16) float b_s[D];
    __shared__ float e_s[K], att_s[K], A_s[K], B_s[K], R_s[K];
    __shared__ int   adj_s[K];

    const int n  = blockIdx.x;
    const int t  = threadIdx.x;
    const int w  = t >> 6;        // wave 0..7
    const int l  = t & 63;        // lane
    const int lr = l & 15;        // tile row index
    const int lk = l >> 4;        // k-quad 0..3

    const float* dstn = dst + (size_t)n * K * D;
    const float* reln = rel + (size_t)n * K * D;

    // ==== phase A: stage src,b,adj,dst,rel  +  sW1 partials (overlapped) ====
    if (t < 32)       ((float4*)x_s)[t]      = ((const float4*)(src + (size_t)n * D))[t];
    else if (t < 64)  ((float4*)b_s)[t - 32] = ((const float4*)b)[t - 32];
    else if (t < 96)  adj_s[t - 64] = adj[n * K + (t - 64)];
    #pragma unroll
    for (int jj = 0; jj < 2; ++jj) {
        const int idx = t + 512 * jj;          // [0, K*D/4)
        const int row = idx >> 5, col = idx & 31;
        *(float4*)(dst_s + row * DP + 4 * col) = ((const float4*)dstn)[idx];
        *(float4*)(rel_s + row * DP + 4 * col) = ((const float4*)reln)[idx];
    }
    {   // sW1 partial: e-quarter es, output dd; src read from global (L2/L3-hot)
        const int dd = t & 127, es = t >> 7;
        const float* srcp = src + (size_t)n * D + 32 * es;
        const float* Wp   = W + (size_t)(32 * es) * D + dd;
        float acc = 0.f;
        #pragma unroll 8
        for (int e = 0; e < 32; ++e)
            acc = fmaf(srcp[e], Wp[(size_t)e * D], acc);
        sWp[es * D + dd] = acc;
    }
    __syncthreads();

    // ==== phase B: combine sW1 ====
    if (t < D) sW_s[t] = (sWp[t] + sWp[D + t]) + (sWp[2 * D + t] + sWp[3 * D + t]);
    __syncthreads();

    // ==== phase C: hd = dst@W_bot + b via split-bf16 MFMA; wave owns nt=w ====
    {
        f32x4 acc0 = {0,0,0,0}, acc1 = {0,0,0,0};     // mtile 0 (k 0-15), 1 (k 16-31)
        #pragma unroll
        for (int ks = 0; ks < 4; ++ks) {               // e-steps of 32
            const int cb = 32 * ks + 8 * lk;
            bf16x8 ah0, al0, ah1, al1;                 // A-frags rows lr, 16+lr
            {
                const float* p0 = dst_s + lr * DP + cb;
                const float* p1 = dst_s + (16 + lr) * DP + cb;
                const f32x4 x0 = *(const f32x4*)p0, x1 = *(const f32x4*)(p0 + 4);
                const f32x4 y0 = *(const f32x4*)p1, y1 = *(const f32x4*)(p1 + 4);
                #pragma unroll
                for (int jj = 0; jj < 4; ++jj) {
                    float v; __bf16 h;
                    v = x0[jj]; h = (__bf16)v; ah0[jj]     = h; al0[jj]     = (__bf16)(v - (float)h);
                    v = x1[jj]; h = (__bf16)v; ah0[4 + jj] = h; al0[4 + jj] = (__bf16)(v - (float)h);
                    v = y0[jj]; h = (__bf16)v; ah1[jj]     = h; al1[jj]     = (__bf16)(v - (float)h);
                    v = y1[jj]; h = (__bf16)v; ah1[4 + jj] = h; al1[4 + jj] = (__bf16)(v - (float)h);
                }
            }
            const size_t fo = (size_t)((ks * 8 + w) * 64 + l) * 8;
            const bf16x8 bh = *(const bf16x8*)(whi + fo);
            const bf16x8 bl = *(const bf16x8*)(wlo + fo);
            acc0 = __builtin_amdgcn_mfma_f32_16x16x32_bf16(ah0, bh, acc0, 0, 0, 0);
            acc0 = __builtin_amdgcn_mfma_f32_16x16x32_bf16(ah0, bl, acc0, 0, 0, 0);
            acc0 = __builtin_amdgcn_mfma_f32_16x16x32_bf16(al0, bh, acc0, 0, 0, 0);
            acc1 = __builtin_amdgcn_mfma_f32_16x16x32_bf16(ah1, bh, acc1, 0, 0, 0);
            acc1 = __builtin_amdgcn_mfma_f32_16x16x32_bf16(ah1, bl, acc1, 0, 0, 0);
            acc1 = __builtin_amdgcn_mfma_f32_16x16x32_bf16(al1, bh, acc1, 0, 0, 0);
        }
        // C/D layout (m89): col = lane&15, row = (lane>>4)*4 + reg.
        const float bc = b_s[16 * w + lr];
        #pragma unroll
        for (int r = 0; r < 4; ++r) {
            hd_s[(4 * lk + r) * DP + 16 * w + lr]      = acc0[r] + bc;
            hd_s[(16 + 4 * lk + r) * DP + 16 * w + lr] = acc1[r] + bc;
        }
    }
    __syncthreads();

    // per-k dot mapping: wave w owns k = 4w + (l&3); 16 lanes/k, quad q2 = l>>2.
    const int kc = 4 * w + (l & 3);
    const int q2 = l >> 2;

    // ==== phase D: layer-1 scalars + e1; cache A,B,R ====
    {
        float a_ = 0.f, bb = 0.f, r2 = 0.f, sr = 0.f, sh = 0.f, ss = 0.f;
        #pragma unroll
        for (int it = 0; it < 2; ++it) {
            const int f = q2 + 16 * it;
            const float4 rv = *(const float4*)(rel_s + kc * DP + 4 * f);
            const float4 hv = *(const float4*)(hd_s + kc * DP + 4 * f);
            const float4 sv = ((const float4*)sW_s)[f];
            a_ += dot4(hv, rv);  bb += dot4(hv, hv);  r2 += dot4(rv, rv);
            sr += dot4(sv, rv);  sh += dot4(sv, hv);  ss += dot4(sv, sv);
        }
        #pragma unroll
        for (int m = 4; m < 64; m <<= 1) {
            a_ += __shfl_xor(a_, m);  bb += __shfl_xor(bb, m);
            r2 += __shfl_xor(r2, m);  sr += __shfl_xor(sr, m);
            sh += __shfl_xor(sh, m);  ss += __shfl_xor(ss, m);
        }
        if (q2 == 0) {
            const float R   = fmaxf(sqrtf(r2), EPS);
            const float hh  = ss + 2.f * sh + bb;          // ||h1||^2
            const float den = fmaxf(sqrtf(hh), EPS) * R;
            float e = (sr + a_) / den;
            e = e > 0.f ? e : ALPHA * e;                   // LeakyReLU
            if (adj_s[kc] <= 0) e = MASKV;                 // mask
            e_s[kc] = e;  A_s[kc] = a_;  B_s[kc] = bb;  R_s[kc] = R;
        }
    }
    __syncthreads();

    // ==== phase E: softmax1 ====
    if (t < K) {
        float v = e_s[t], m = v;
        #pragma unroll
        for (int s = 16; s > 0; s >>= 1) m = fmaxf(m, __shfl_xor(m, s));
        const float p = expf(v - m);
        float sm = p;
        #pragma unroll
        for (int s = 16; s > 0; s >>= 1) sm += __shfl_xor(sm, s);
        att_s[t] = p / sm;
    }
    __syncthreads();

    // ==== phase F: x1 = agg1 + src ====
    if (t < D) {
        float agg = 0.f;
        #pragma unroll
        for (int k = 0; k < K; ++k) agg = fmaf(att_s[k], dst_s[k * DP + t], agg);
        x_s[t] = agg + x_s[t];
    }
    __syncthreads();

    // ==== phase G: sW2 partials (x1 from LDS broadcast) ====
    {
        const int dd = t & 127, es = t >> 7;
        const float* Wp = W + (size_t)(32 * es) * D + dd;
        float acc = 0.f;
        #pragma unroll 8
        for (int e = 0; e < 32; ++e)
            acc = fmaf(x_s[32 * es + e], Wp[(size_t)e * D], acc);
        sWp[es * D + dd] = acc;
    }
    __syncthreads();

    // ==== phase H: combine sW2 ====
    if (t < D) sW_s[t] = (sWp[t] + sWp[D + t]) + (sWp[2 * D + t] + sWp[3 * D + t]);
    __syncthreads();

    // ==== phase I: layer-2 scalars + e2 (hd_s reused; A,B,R cached) ====
    {
        float sr = 0.f, sh = 0.f, ss = 0.f;
        #pragma unroll
        for (int it = 0; it < 2; ++it) {
            const int f = q2 + 16 * it;
            const float4 rv = *(const float4*)(rel_s + kc * DP + 4 * f);
            const float4 hv = *(const float4*)(hd_s + kc * DP + 4 * f);
            const float4 sv = ((const float4*)sW_s)[f];
            sr += dot4(sv, rv);  sh += dot4(sv, hv);  ss += dot4(sv, sv);
        }
        #pragma unroll
        for (int m = 4; m < 64; m <<= 1) {
            sr += __shfl_xor(sr, m);  sh += __shfl_xor(sh, m);  ss += __shfl_xor(ss, m);
        }
        if (q2 == 0) {
            const float hh  = ss + 2.f * sh + B_s[kc];     // ||h2||^2
            const float den = fmaxf(sqrtf(hh), EPS) * R_s[kc];
            float e = (sr + A_s[kc]) / den;
            e = e > 0.f ? e : ALPHA * e;
            if (adj_s[kc] <= 0) e = MASKV;
            e_s[kc] = e;
        }
    }
    __syncthreads();

    // ==== phase J: softmax2 ====
    if (t < K) {
        float v = e_s[t], m = v;
        #pragma unroll
        for (int s = 16; s > 0; s >>= 1) m = fmaxf(m, __shfl_xor(m, s));
        const float p = expf(v - m);
        float sm = p;
        #pragma unroll
        for (int s = 16; s > 0; s >>= 1) sm += __shfl_xor(sm, s);
        att_s[t] = p / sm;
    }
    __syncthreads();

    // ==== phase K: out = agg2 + x1 ====
    if (t < D) {
        float agg = 0.f;
        #pragma unroll
        for (int k = 0; k < K; ++k) agg = fmaf(att_s[k], dst_s[k * DP + t], agg);
        out[(size_t)n * D + t] = agg + x_s[t];
    }
}

extern "C" void kernel_launch(void* const* d_in, const int* in_sizes, int n_in,
                              void* d_out, int out_size, void* d_ws, size_t ws_size,
                              hipStream_t stream) {
    const float* src = (const float*)d_in[0];
    const float* dst = (const float*)d_in[1];
    const float* rel = (const float*)d_in[2];
    const float* W   = (const float*)d_in[3];
    const float* b   = (const float*)d_in[4];
    const int*   adj = (const int*)d_in[5];
    float* out = (float*)d_out;

    __bf16* whi = (__bf16*)d_ws;            // 16384 bf16 = 32 KB
    __bf16* wlo = whi + 4 * 8 * 64 * 8;     // +32 KB

    conv_w<<<64, 256, 0, stream>>>(W, whi, wlo);
    gat_fused<<<NN, 512, 0, stream>>>(src, dst, rel, W, b, adj, whi, wlo, out);
}

// Round 7
// 352.319 us; speedup vs baseline: 1.6535x; 1.0609x over previous
//
#include <hip/hip_runtime.h>
#include <math.h>

// Problem constants (reference setup_inputs): N=8192, K=32, D=128, fp32.
constexpr int NN = 8192;
constexpr int K  = 32;
constexpr int D  = 128;
constexpr int HS  = 136;   // bf16 plane row stride (elems): 272 B (16B-mult, bank-rotating)
constexpr int HDS = 132;   // hd_s f32 row stride (bank-rotating)
constexpr float ALPHA = 0.2f;
constexpr float MASKV = -9e15f;
constexpr float EPS   = 1e-8f;

typedef __bf16 bf16x8 __attribute__((ext_vector_type(8)));
typedef __bf16 bf16x4 __attribute__((ext_vector_type(4)));
typedef float  f32x4  __attribute__((ext_vector_type(4)));

__device__ __forceinline__ float dot4v(const f32x4 a, const f32x4 b) {
    return fmaf(a[0], b[0], fmaf(a[1], b[1], fmaf(a[2], b[2], a[3] * b[3])));
}

// ---------------------------------------------------------------------------
// Pre-kernel: build MFMA-fragment-ordered bf16 hi/lo tables for BOTH W halves.
// tabs = [bot_hi | bot_lo | top_hi | top_lo], 16384 elems each.
// Fragment (s,nt): lane l, elem j = W[rowbase + 32s + 8*(l>>4) + j][16nt + (l&15)].
// ---------------------------------------------------------------------------
__global__ __launch_bounds__(256) void conv_w(const float* __restrict__ W,
                                              __bf16* __restrict__ tabs) {
    const int idx = blockIdx.x * 256 + threadIdx.x;      // 32768 total
    const int j = idx & 7, l = (idx >> 3) & 63, nt = (idx >> 9) & 7;
    const int s = (idx >> 12) & 3, half = idx >> 14;     // 0 = bot(W[D:2D]), 1 = top(W[0:D])
    const int e = 32 * s + 8 * (l >> 4) + j;
    const int c = 16 * nt + (l & 15);
    const float x = W[(size_t)((half ? 0 : D) + e) * D + c];
    const __bf16 h = (__bf16)x;
    const int fi = idx & 16383;
    tabs[half * 32768 + fi]         = h;
    tabs[half * 32768 + 16384 + fi] = (__bf16)(x - (float)h);
}

// ---------------------------------------------------------------------------
// Fused 2-layer GAT-relation, one 512-thread block per n, 4 blocks/CU.
// Phase A: stage dst (as bf16 hi/lo planes), src, b, adj; rel -> REGISTERS;
//          sW1 = src@W_top partials (4-way e-split).
// Phase C: split-bf16 MFMA: hd = dst@W_bot (+b) -> LDS;  dstWt = dst@W_top
//          stays in registers (acc2/acc3).
// Phase D: layer-1 cosine scalars from {hd, rel(reg), sW1}; cache A,B,R.
// E: softmax1.  G': sW2 = Sum att1_k*dstWt[k] + sW1 (registers + 2 shuffles).
// I: layer-2 scalars (rel regs reused, hd LDS, A/B/R cached).  J: softmax2.
// K: out = Sum_k (att1_k+att2_k)*dst_k + src   (x1 never materialized).
// ---------------------------------------------------------------------------
__global__ __launch_bounds__(512, 8) void gat_fused(
    const float* __restrict__ src,
    const float* __restrict__ dst,
    const float* __restrict__ rel,
    const float* __restrict__ W,
    const float* __restrict__ b,
    const int*   __restrict__ adj,
    const __bf16* __restrict__ tabs,
    float* __restrict__ out)
{
    __shared__ __align__(16) __bf16 hi_s[K * HS];   // 8704 B
    __shared__ __align__(16) __bf16 lo_s[K * HS];   // 8704 B
    __shared__ __align__(16) float  hd_s[K * HDS];  // 16896 B
    __shared__ __align__(16) float  x_s[D];         // src
    __shared__ __align__(16) float  sWp[4 * D];     // sW1 e-split partials
    __shared__ __align__(16) float  sW_s[D];        // sW2
    __shared__ __align__(16) float  b_s[D];
    __shared__ float e_s[K], att1_s[K], ats_s[K], A_s[K], B_s[K], R_s[K];
    __shared__ int   adj_s[K];

    const int n  = blockIdx.x;
    const int t  = threadIdx.x;
    const int w  = t >> 6;        // wave 0..7
    const int l  = t & 63;
    const int lr = l & 15;        // MFMA tile row/col
    const int lk = l >> 4;        // MFMA k-quad
    const int kc = 4 * w + (l & 3);  // dot-phase k (16 lanes per k)
    const int q2 = l >> 2;           // dot-phase elem-quad 0..15

    const float* dstn = dst + (size_t)n * K * D;
    const float* reln = rel + (size_t)n * K * D;
    const __bf16* wbh = tabs;
    const __bf16* wbl = tabs + 16384;
    const __bf16* wth = tabs + 32768;
    const __bf16* wtl = tabs + 49152;

    // ==== phase A: stage + rel->regs + sW1 partials ====
    if (t < 32)       ((float4*)x_s)[t]      = ((const float4*)(src + (size_t)n * D))[t];
    else if (t < 64)  ((float4*)b_s)[t - 32] = ((const float4*)b)[t - 32];
    else if (t < 96)  adj_s[t - 64] = adj[n * K + (t - 64)];

    // rel for this thread's (kc, q2) — held in registers through D and I.
    const f32x4 rv0 = *(const f32x4*)(reln + kc * D + 4 * q2);
    const f32x4 rv1 = *(const f32x4*)(reln + kc * D + 4 * (q2 + 16));

    #pragma unroll
    for (int jj = 0; jj < 2; ++jj) {
        const int idx = t + 512 * jj;          // [0, K*D/4)
        const int row = idx >> 5, c4 = idx & 31;
        const float4 g = ((const float4*)dstn)[idx];
        const float gv[4] = {g.x, g.y, g.z, g.w};
        bf16x4 hv, lv;
        #pragma unroll
        for (int c = 0; c < 4; ++c) {
            const __bf16 h = (__bf16)gv[c];
            hv[c] = h;
            lv[c] = (__bf16)(gv[c] - (float)h);
        }
        *(bf16x4*)(hi_s + row * HS + 4 * c4) = hv;
        *(bf16x4*)(lo_s + row * HS + 4 * c4) = lv;
    }
    {   // sW1 partial: e-quarter es, output col dd (W coalesced over dd)
        const int dd = t & 127, es = t >> 7;
        const float* sp = src + (size_t)n * D + 32 * es;
        const float* Wp = W + (size_t)(32 * es) * D + dd;
        float acc = 0.f;
        #pragma unroll 8
        for (int e = 0; e < 32; ++e)
            acc = fmaf(sp[e], Wp[(size_t)e * D], acc);
        sWp[es * D + dd] = acc;
    }
    __syncthreads();   // B1

    // ==== phase C: MFMA — hd (bot) to LDS, dstWt (top) to registers ====
    f32x4 acc2 = {0,0,0,0}, acc3 = {0,0,0,0};       // dstWt k 0-15 / 16-31
    {
        f32x4 acc0 = {0,0,0,0}, acc1 = {0,0,0,0};   // hd k 0-15 / 16-31
        #pragma unroll
        for (int ks = 0; ks < 4; ++ks) {
            const int off = lr * HS + 32 * ks + 8 * lk;
            const bf16x8 ah0 = *(const bf16x8*)(hi_s + off);
            const bf16x8 al0 = *(const bf16x8*)(lo_s + off);
            const bf16x8 ah1 = *(const bf16x8*)(hi_s + off + 16 * HS);
            const bf16x8 al1 = *(const bf16x8*)(lo_s + off + 16 * HS);
            const size_t fo = (size_t)((ks * 8 + w) * 64 + l) * 8;
            {
                const bf16x8 bh = *(const bf16x8*)(wbh + fo);
                const bf16x8 bl = *(const bf16x8*)(wbl + fo);
                acc0 = __builtin_amdgcn_mfma_f32_16x16x32_bf16(ah0, bh, acc0, 0, 0, 0);
                acc0 = __builtin_amdgcn_mfma_f32_16x16x32_bf16(ah0, bl, acc0, 0, 0, 0);
                acc0 = __builtin_amdgcn_mfma_f32_16x16x32_bf16(al0, bh, acc0, 0, 0, 0);
                acc1 = __builtin_amdgcn_mfma_f32_16x16x32_bf16(ah1, bh, acc1, 0, 0, 0);
                acc1 = __builtin_amdgcn_mfma_f32_16x16x32_bf16(ah1, bl, acc1, 0, 0, 0);
                acc1 = __builtin_amdgcn_mfma_f32_16x16x32_bf16(al1, bh, acc1, 0, 0, 0);
            }
            {
                const bf16x8 th = *(const bf16x8*)(wth + fo);
                const bf16x8 tl = *(const bf16x8*)(wtl + fo);
                acc2 = __builtin_amdgcn_mfma_f32_16x16x32_bf16(ah0, th, acc2, 0, 0, 0);
                acc2 = __builtin_amdgcn_mfma_f32_16x16x32_bf16(ah0, tl, acc2, 0, 0, 0);
                acc2 = __builtin_amdgcn_mfma_f32_16x16x32_bf16(al0, th, acc2, 0, 0, 0);
                acc3 = __builtin_amdgcn_mfma_f32_16x16x32_bf16(ah1, th, acc3, 0, 0, 0);
                acc3 = __builtin_amdgcn_mfma_f32_16x16x32_bf16(ah1, tl, acc3, 0, 0, 0);
                acc3 = __builtin_amdgcn_mfma_f32_16x16x32_bf16(al1, tl, acc3, 0, 0, 0);
            }
        }
        // C/D layout (m89): col = lane&15, row = (lane>>4)*4 + reg
        const float bc = b_s[16 * w + lr];
        #pragma unroll
        for (int r = 0; r < 4; ++r) {
            hd_s[(4 * lk + r) * HDS + 16 * w + lr]      = acc0[r] + bc;
            hd_s[(16 + 4 * lk + r) * HDS + 16 * w + lr] = acc1[r] + bc;
        }
    }
    __syncthreads();   // B2

    // ==== phase D: layer-1 scalars + e1; cache A,B,R ====
    {
        float a_ = 0.f, bb = 0.f, r2 = 0.f, sr = 0.f, sh = 0.f, ss = 0.f;
        #pragma unroll
        for (int it = 0; it < 2; ++it) {
            const int f = q2 + 16 * it;
            const f32x4 rv = it ? rv1 : rv0;
            const f32x4 hv = *(const f32x4*)(hd_s + kc * HDS + 4 * f);
            f32x4 sv = ((const f32x4*)sWp)[f];
            sv += ((const f32x4*)sWp)[32 + f];
            sv += ((const f32x4*)sWp)[64 + f];
            sv += ((const f32x4*)sWp)[96 + f];
            a_ += dot4v(hv, rv);  bb += dot4v(hv, hv);  r2 += dot4v(rv, rv);
            sr += dot4v(sv, rv);  sh += dot4v(sv, hv);  ss += dot4v(sv, sv);
        }
        #pragma unroll
        for (int m = 4; m < 64; m <<= 1) {
            a_ += __shfl_xor(a_, m);  bb += __shfl_xor(bb, m);
            r2 += __shfl_xor(r2, m);  sr += __shfl_xor(sr, m);
            sh += __shfl_xor(sh, m);  ss += __shfl_xor(ss, m);
        }
        if (q2 == 0) {
            const float R   = fmaxf(sqrtf(r2), EPS);
            const float hh  = ss + 2.f * sh + bb;          // ||h1||^2
            const float den = fmaxf(sqrtf(hh), EPS) * R;
            float e = (sr + a_) / den;
            e = e > 0.f ? e : ALPHA * e;                   // LeakyReLU
            if (adj_s[kc] <= 0) e = MASKV;                 // mask
            e_s[kc] = e;  A_s[kc] = a_;  B_s[kc] = bb;  R_s[kc] = R;
        }
    }
    __syncthreads();   // B3

    // ==== phase E: softmax1 -> att1 ====
    if (t < K) {
        float v = e_s[t], m = v;
        #pragma unroll
        for (int s = 16; s > 0; s >>= 1) m = fmaxf(m, __shfl_xor(m, s));
        const float p = expf(v - m);
        float sm = p;
        #pragma unroll
        for (int s = 16; s > 0; s >>= 1) sm += __shfl_xor(sm, s);
        att1_s[t] = p / sm;
    }
    __syncthreads();   // B4

    // ==== phase G': sW2 = Sum_k att1_k * dstWt[k][col] + sW1[col] ====
    {
        float s2 = 0.f;
        #pragma unroll
        for (int r = 0; r < 4; ++r) {
            s2 = fmaf(att1_s[4 * lk + r],      acc2[r], s2);
            s2 = fmaf(att1_s[16 + 4 * lk + r], acc3[r], s2);
        }
        s2 += __shfl_xor(s2, 16);
        s2 += __shfl_xor(s2, 32);
        if (lk == 0) {
            const int col = 16 * w + lr;
            sW_s[col] = s2 + ((sWp[col] + sWp[128 + col]) +
                              (sWp[256 + col] + sWp[384 + col]));
        }
    }
    __syncthreads();   // B5

    // ==== phase I: layer-2 scalars + e2 (rel regs, hd LDS, A/B/R cached) ====
    {
        float sr = 0.f, sh = 0.f, ss = 0.f;
        #pragma unroll
        for (int it = 0; it < 2; ++it) {
            const int f = q2 + 16 * it;
            const f32x4 rv = it ? rv1 : rv0;
            const f32x4 hv = *(const f32x4*)(hd_s + kc * HDS + 4 * f);
            const f32x4 sv = ((const f32x4*)sW_s)[f];
            sr += dot4v(sv, rv);  sh += dot4v(sv, hv);  ss += dot4v(sv, sv);
        }
        #pragma unroll
        for (int m = 4; m < 64; m <<= 1) {
            sr += __shfl_xor(sr, m);  sh += __shfl_xor(sh, m);  ss += __shfl_xor(ss, m);
        }
        if (q2 == 0) {
            const float hh  = ss + 2.f * sh + B_s[kc];     // ||h2||^2
            const float den = fmaxf(sqrtf(hh), EPS) * R_s[kc];
            float e = (sr + A_s[kc]) / den;
            e = e > 0.f ? e : ALPHA * e;
            if (adj_s[kc] <= 0) e = MASKV;
            e_s[kc] = e;
        }
    }
    __syncthreads();   // B6

    // ==== phase J: softmax2 -> attsum = att1 + att2 ====
    if (t < K) {
        float v = e_s[t], m = v;
        #pragma unroll
        for (int s = 16; s > 0; s >>= 1) m = fmaxf(m, __shfl_xor(m, s));
        const float p = expf(v - m);
        float sm = p;
        #pragma unroll
        for (int s = 16; s > 0; s >>= 1) sm += __shfl_xor(sm, s);
        ats_s[t] = att1_s[t] + p / sm;
    }
    __syncthreads();   // B7

    // ==== phase K: out = Sum_k attsum_k * dst_k + src ====
    if (t < D) {
        float agg = 0.f;
        #pragma unroll
        for (int k = 0; k < K; ++k) {
            const float f = (float)hi_s[k * HS + t] + (float)lo_s[k * HS + t];
            agg = fmaf(ats_s[k], f, agg);
        }
        out[(size_t)n * D + t] = agg + x_s[t];
    }
}

extern "C" void kernel_launch(void* const* d_in, const int* in_sizes, int n_in,
                              void* d_out, int out_size, void* d_ws, size_t ws_size,
                              hipStream_t stream) {
    const float* src = (const float*)d_in[0];
    const float* dst = (const float*)d_in[1];
    const float* rel = (const float*)d_in[2];
    const float* W   = (const float*)d_in[3];
    const float* b   = (const float*)d_in[4];
    const int*   adj = (const int*)d_in[5];
    float* out = (float*)d_out;

    __bf16* tabs = (__bf16*)d_ws;   // 4 x 16384 bf16 = 128 KB

    conv_w<<<128, 256, 0, stream>>>(W, tabs);
    gat_fused<<<NN, 512, 0, stream>>>(src, dst, rel, W, b, adj, tabs, out);
}